// Round 3
// baseline (281.369 us; speedup 1.0000x reference)
//
#include <hip/hip_runtime.h>
#include <hip/hip_bf16.h>

// LinearAttention on MI355X (gfx950). Inputs/outputs fp32; internal bf16 MFMA.
// B=4 N=4096 C=1024 H=16 D=64.
// Pipeline:
//  K0 cvt:            xb/wqkvb/wprojb = bf16(x / w_qkv / w_proj)
//  K1 gemm_bt<16384>: QKV^T[c, m] = sum_k w_qkv[c,k] * x[m,k], relu on c<2048 rows.
//  K2 ctx_kernel:     per (b,h,s): partial ctx[d,e] = sum_n V[d,n]K[e,n], partial ksum.
//  K3 out_kernel:     O[m, h*64+d] = z[n] * sum_e ctx[d,e] Q[e,n]   (bf16)
//  K4 gemm_bt<1024>:  out[m,co] = sum_c O[m,c] w_proj[co,c] + b_proj[co]  (fp32 out)
// Deterministic: no atomics; every ws region fully written before read.

typedef __bf16 bf16;
typedef __bf16 bf16x8 __attribute__((ext_vector_type(8)));
typedef __bf16 bf16x4 __attribute__((ext_vector_type(4)));
typedef float  f32x4  __attribute__((ext_vector_type(4)));

#define MFMA16(a, b, c) __builtin_amdgcn_mfma_f32_16x16x32_bf16((a), (b), (c), 0, 0, 0)

__device__ __forceinline__ void gload_lds16(const bf16* g, bf16* l) {
  // 16B per lane; LDS dest = wave-uniform base + lane*16 (linear layout required).
  __builtin_amdgcn_global_load_lds(
      (const __attribute__((address_space(1))) void*)g,
      (__attribute__((address_space(3))) void*)l, 16, 0, 0);
}

// ---------------------------------------------------------------------------
// K0: fp32 -> bf16 elementwise convert (float4 in, bf16x4 out), grid-stride.
// ---------------------------------------------------------------------------
__global__ __launch_bounds__(256) void cvt_f32_bf16(const float* __restrict__ src,
                                                    bf16* __restrict__ dst, long n) {
  const long stride4 = (long)gridDim.x * blockDim.x * 4;
  for (long j = ((long)blockIdx.x * blockDim.x + threadIdx.x) * 4; j < n; j += stride4) {
    const float4 v = *(const float4*)(src + j);
    bf16x4 o;
    o[0] = (bf16)v.x; o[1] = (bf16)v.y; o[2] = (bf16)v.z; o[3] = (bf16)v.w;
    *(bf16x4*)(dst + j) = o;
  }
}

// ---------------------------------------------------------------------------
// C[i, j] = sum_k A[i,k] * B[j,k]   (A: [Mi,1024], B: [Nj,1024], bf16 row-major)
// m97 structure: 128x128 tile, BK=32, 4 waves (2x2), global_load_lds width 16.
// CO = bf16 (K1) or float (K4 final output).
// ---------------------------------------------------------------------------
template <int LDC, typename CO>
__global__ __launch_bounds__(256) void gemm_bt(const bf16* __restrict__ A,
                                               const bf16* __restrict__ Bm,
                                               CO* __restrict__ Co,
                                               const float* __restrict__ bias,
                                               const int reluRows) {
  __shared__ bf16 As[128 * 32];
  __shared__ bf16 Bs[128 * 32];
  const int tid  = threadIdx.x;
  const int lane = tid & 63;
  const int w    = tid >> 6;        // wave 0..3
  const int wr   = w >> 1;          // 2x2 wave grid
  const int wc   = w & 1;
  const int i0 = blockIdx.y * 128;  // A-row block
  const int j0 = blockIdx.x * 128;  // B-row block

  // staging: per wave 2 instructions per tile, 16 rows (4 lanes/row) each
  const int srow = lane >> 2;
  const int scol = (lane & 3) * 8;
  const bf16* Ag = A  + (long)(i0 + w * 32 + srow) * 1024 + scol;
  const bf16* Bg = Bm + (long)(j0 + w * 32 + srow) * 1024 + scol;
  bf16* Asw = As + w * 32 * 32;
  bf16* Bsw = Bs + w * 32 * 32;

  const int r15  = lane & 15;
  const int koff = (lane >> 4) * 8;

  f32x4 acc[4][4] = {};

  for (int kk = 0; kk < 1024; kk += 32) {
    gload_lds16(Ag + kk,             Asw);
    gload_lds16(Ag + kk + 16 * 1024, Asw + 16 * 32);
    gload_lds16(Bg + kk,             Bsw);
    gload_lds16(Bg + kk + 16 * 1024, Bsw + 16 * 32);
    __syncthreads();  // drains vmcnt (compiler emits waitcnt before s_barrier)
    bf16x8 af[4], bfm[4];
#pragma unroll
    for (int t = 0; t < 4; ++t)
      af[t] = *(const bf16x8*)(As + (wr * 64 + t * 16 + r15) * 32 + koff);
#pragma unroll
    for (int u = 0; u < 4; ++u)
      bfm[u] = *(const bf16x8*)(Bs + (wc * 64 + u * 16 + r15) * 32 + koff);
#pragma unroll
    for (int t = 0; t < 4; ++t)
#pragma unroll
      for (int u = 0; u < 4; ++u)
        acc[t][u] = MFMA16(af[t], bfm[u], acc[t][u]);
    __syncthreads();
  }

  // D layout per 16x16 tile: row = (lane>>4)*4 + jj, col = lane&15
  const bool doRelu = (i0 < reluRows);  // block-uniform (128 | reluRows)
  const int rbase = i0 + wr * 64;
  const int cbase = j0 + wc * 64;
#pragma unroll
  for (int t = 0; t < 4; ++t) {
    const int r0 = rbase + t * 16 + (lane >> 4) * 4;
#pragma unroll
    for (int u = 0; u < 4; ++u) {
      const int cc = cbase + u * 16 + r15;
      const float bv = bias ? bias[cc] : 0.0f;
#pragma unroll
      for (int jj = 0; jj < 4; ++jj) {
        float v = acc[t][u][jj] + bv;
        if (doRelu) v = fmaxf(v, 0.0f);
        Co[(long)(r0 + jj) * LDC + cc] = (CO)v;
      }
    }
  }
}

// ---------------------------------------------------------------------------
// K2: per (b,h) n-chunk s (512 cols): partial ctx[d,e] += V[d,n]*K[e,n],
//     partial ksum[e] += K[e,n].  Direct global->MFMA (no LDS), deterministic.
// ---------------------------------------------------------------------------
__global__ __launch_bounds__(256) void ctx_kernel(const bf16* __restrict__ QKV,
                                                  float* __restrict__ ctx_part,
                                                  float* __restrict__ ksum_part) {
  const int bh = blockIdx.x;  // 0..63
  const int s  = blockIdx.y;  // 0..7
  const int b  = bh >> 4, h = bh & 15;
  const int tid = threadIdx.x, lane = tid & 63, w = tid >> 6;
  const long ldq = 16384;
  const bf16* Kp = QKV + (long)(1024 + h * 64) * ldq + b * 4096 + s * 512;
  const bf16* Vp = QKV + (long)(2048 + h * 64) * ldq + b * 4096 + s * 512;

  const int r15  = lane & 15;
  const int koff = (lane >> 4) * 8;

  f32x4 acc[4] = {};  // wave w owns d rows [w*16, w*16+16), 4 e-tiles
#pragma unroll 4
  for (int n = 0; n < 512; n += 32) {
    const bf16x8 a = *(const bf16x8*)(Vp + (long)(w * 16 + r15) * ldq + n + koff);
#pragma unroll
    for (int u = 0; u < 4; ++u) {
      const bf16x8 kb = *(const bf16x8*)(Kp + (long)(u * 16 + r15) * ldq + n + koff);
      acc[u] = MFMA16(a, kb, acc[u]);
    }
  }
  float* cp = ctx_part + (long)(bh * 8 + s) * 4096;
#pragma unroll
  for (int u = 0; u < 4; ++u)
#pragma unroll
    for (int jj = 0; jj < 4; ++jj) {
      const int d = w * 16 + (lane >> 4) * 4 + jj;
      const int e = u * 16 + r15;
      cp[d * 64 + e] = acc[u][jj];
    }

  // ksum partial: 4 threads per e-row, 128 cols each
  const int e = tid >> 2, q4 = tid & 3;
  const bf16* kr = Kp + (long)e * ldq + q4 * 128;
  float sum = 0.0f;
#pragma unroll
  for (int i = 0; i < 128; i += 8) {
    const bf16x8 v = *(const bf16x8*)(kr + i);
#pragma unroll
    for (int jj = 0; jj < 8; ++jj) sum += (float)v[jj];
  }
  sum += __shfl_xor(sum, 1);
  sum += __shfl_xor(sum, 2);
  if (q4 == 0) ksum_part[(bh * 8 + s) * 64 + e] = sum;
}

// ---------------------------------------------------------------------------
// K3: per (b,h), 256-col n-chunk: O[(b,n), h*64+d] = z[n]*sum_e ctx[d,e]Q[e,n]
// ---------------------------------------------------------------------------
__global__ __launch_bounds__(256) void out_kernel(const bf16* __restrict__ QKV,
                                                  const float* __restrict__ ctx_part,
                                                  const float* __restrict__ ksum_part,
                                                  bf16* __restrict__ O) {
  __shared__ bf16 ctx_lds[64 * 88];   // [d][e], stride 88 (176B, 16B-mult, ~2-way)
  __shared__ bf16 qlds[256 * 80];     // [n_local][e], stride 80 (160B, 16B-mult)
  __shared__ float ksum_lds[64];
  __shared__ float zlds[256];

  const int nc = blockIdx.x;  // 0..15
  const int bh = blockIdx.y;  // 0..63
  const int b = bh >> 4, h = bh & 15;
  const int tid = threadIdx.x, lane = tid & 63, w = tid >> 6;
  const int n0 = nc * 256;
  const long ldq = 16384;

  // 1) sum 8 ctx partials -> bf16 LDS
  const float* cp = ctx_part + (long)bh * 8 * 4096;
#pragma unroll
  for (int r = 0; r < 16; ++r) {
    const int idx = tid + r * 256;  // = d*64 + e
    float v = 0.0f;
#pragma unroll
    for (int s2 = 0; s2 < 8; ++s2) v += cp[s2 * 4096 + idx];
    ctx_lds[(idx >> 6) * 88 + (idx & 63)] = (bf16)v;
  }
  if (tid < 64) {
    float v = 0.0f;
#pragma unroll
    for (int s2 = 0; s2 < 8; ++s2) v += ksum_part[(bh * 8 + s2) * 64 + tid];
    ksum_lds[tid] = v;
  }
  // 2) stage Q tile transposed: qlds[n][e]
  {
    const bf16* Qp = QKV + (long)(h * 64) * ldq + b * 4096 + n0;
    const int e = tid >> 2, seg = tid & 3;
    const bf16* qr = Qp + (long)e * ldq + seg * 64;
#pragma unroll
    for (int i = 0; i < 64; i += 8) {
      const bf16x8 v = *(const bf16x8*)(qr + i);
#pragma unroll
      for (int jj = 0; jj < 8; ++jj) qlds[(seg * 64 + i + jj) * 80 + e] = v[jj];
    }
  }
  __syncthreads();

  // 3) z[n] = 1/(ksum . Q[:,n] + eps)
  {
    float a = 0.0f;
    const bf16* qrow = qlds + tid * 80;
#pragma unroll
    for (int d = 0; d < 64; ++d) a += (float)qrow[d] * ksum_lds[d];
    zlds[tid] = 1.0f / (a + 1.1920929e-07f);
  }
  // A-frags (ctx) once per wave: 4 d-tiles x 2 k(e)-steps
  const int r15 = lane & 15;
  const int koff = (lane >> 4) * 8;
  bf16x8 afr[4][2];
#pragma unroll
  for (int t = 0; t < 4; ++t)
#pragma unroll
    for (int s2 = 0; s2 < 2; ++s2)
      afr[t][s2] = *(const bf16x8*)(ctx_lds + (t * 16 + r15) * 88 + s2 * 32 + koff);
  __syncthreads();

  // 4) each wave: 4 n-tiles of 16
#pragma unroll
  for (int nt = 0; nt < 4; ++nt) {
    const int ntile = w * 4 + nt;
    bf16x8 bfr[2];
#pragma unroll
    for (int s2 = 0; s2 < 2; ++s2)
      bfr[s2] = *(const bf16x8*)(qlds + (ntile * 16 + r15) * 80 + s2 * 32 + koff);
    f32x4 accn[4] = {};
#pragma unroll
    for (int t = 0; t < 4; ++t) {
      accn[t] = MFMA16(afr[t][0], bfr[0], accn[t]);
      accn[t] = MFMA16(afr[t][1], bfr[1], accn[t]);
    }
    const int ncol = n0 + ntile * 16 + r15;
    const float zv = zlds[ntile * 16 + r15];
    bf16* orow = O + (long)(b * 4096 + ncol) * 1024 + h * 64;
#pragma unroll
    for (int t = 0; t < 4; ++t) {
      const int d0 = t * 16 + (lane >> 4) * 4;
      bf16x4 pk;
#pragma unroll
      for (int jj = 0; jj < 4; ++jj) pk[jj] = (bf16)(accn[t][jj] * zv);
      *(bf16x4*)(orow + d0) = pk;  // 8B store, 4 consecutive d
    }
  }
}

// ---------------------------------------------------------------------------
extern "C" void kernel_launch(void* const* d_in, const int* in_sizes, int n_in,
                              void* d_out, int out_size, void* d_ws, size_t ws_size,
                              hipStream_t stream) {
  const float* x      = (const float*)d_in[0];  // [4,4096,1024] fp32
  const float* w_qkv  = (const float*)d_in[1];  // [3072,1024]   fp32
  const float* w_proj = (const float*)d_in[2];  // [1024,1024]   fp32
  const float* b_proj = (const float*)d_in[3];  // [1024]        fp32
  float* out = (float*)d_out;                   // [4,4096,1024] fp32

  char* ws = (char*)d_ws;
  // Layout (xb region reused for O after K1):
  bf16*  QKV       = (bf16*)ws;                               // 96 MiB
  float* ctx_part  = (float*)(ws + 100663296);                // 8 MiB
  float* ksum_part = (float*)(ws + 100663296 + 8388608);      // 128 KiB
  bf16*  xb        = (bf16*)(ws + 109182976);                 // 32 MiB (K1 input)
  bf16*  O         = xb;                                      // reuse after K1
  bf16*  wqkvb     = (bf16*)(ws + 109182976 + 33554432);      // 6 MiB
  bf16*  wprojb    = (bf16*)(ws + 109182976 + 33554432 + 6291456);  // 2 MiB

  // K0: fp32 -> bf16 conversions
  cvt_f32_bf16<<<2048, 256, 0, stream>>>(x,      xb,     16777216);
  cvt_f32_bf16<<<512,  256, 0, stream>>>(w_qkv,  wqkvb,  3145728);
  cvt_f32_bf16<<<256,  256, 0, stream>>>(w_proj, wprojb, 1048576);
  // K1: QKV^T[c,m], relu rows c<2048 (q,k)
  gemm_bt<16384, bf16><<<dim3(128, 24), 256, 0, stream>>>(wqkvb, xb, QKV, nullptr, 2048);
  // K2: partial ctx + ksum
  ctx_kernel<<<dim3(64, 8), 256, 0, stream>>>(QKV, ctx_part, ksum_part);
  // K3: O[m, c]  (overwrites xb region — xb dead after K1)
  out_kernel<<<dim3(16, 64), 256, 0, stream>>>(QKV, ctx_part, ksum_part, O);
  // K4: final projection + bias, fp32 output
  gemm_bt<1024, float><<<dim3(8, 128), 256, 0, stream>>>(O, wprojb, out, b_proj, 0);
}

// Round 4
// 262.870 us; speedup vs baseline: 1.0704x; 1.0704x over previous
//
#include <hip/hip_runtime.h>
#include <hip/hip_bf16.h>

// LinearAttention on MI355X (gfx950). Inputs/outputs fp32; internal bf16 MFMA.
// B=4 N=4096 C=1024 H=16 D=64.
//  K0 cvt:            xb/wqkvb/wprojb = bf16(x / w_qkv / w_proj)
//  K1 gemm256<16384>: QKV^T[c, m] = sum_k w_qkv[c,k] * x[m,k], relu on c<2048 rows.
//  K2 ctx_kernel:     per (b,h,s): partial ctx[d,e] = sum_n V[d,n]K[e,n], partial ksum.
//  K3 out_kernel:     O[m, h*64+d] = z[n] * sum_e ctx[d,e] Q[e,n]   (bf16)
//  K4 gemm256<1024>:  out[m,co] = sum_c O[m,c] w_proj[co,c] + b_proj[co]  (fp32 out)
// gemm256: 256x256 tile, BK=64, 8 waves, double-buffered LDS with counted
// vmcnt(8) prefetch (T3+T4), XOR-swizzled LDS (T2, both-sides), setprio (T5),
// bijective XCD block swizzle (T1). Race-freedom: stage of tile t+1 writes
// buf[t+1 & 1] while compute reads buf[t&1]; end-of-iter lgkmcnt(0)+barrier
// drains all reads of a buffer before any wave re-stages into it.

typedef __bf16 bf16;
typedef __bf16 bf16x8 __attribute__((ext_vector_type(8)));
typedef __bf16 bf16x4 __attribute__((ext_vector_type(4)));
typedef float  f32x4  __attribute__((ext_vector_type(4)));

#define MFMA16(a, b, c) __builtin_amdgcn_mfma_f32_16x16x32_bf16((a), (b), (c), 0, 0, 0)

__device__ __forceinline__ void gload_lds16(const bf16* g, bf16* l) {
  // 16B per lane; LDS dest = wave-uniform base + lane*16 (linear layout required).
  __builtin_amdgcn_global_load_lds(
      (const __attribute__((address_space(1))) void*)g,
      (__attribute__((address_space(3))) void*)l, 16, 0, 0);
}

// ---------------------------------------------------------------------------
// K0: fp32 -> bf16 elementwise convert (float4 in, bf16x4 out), grid-stride.
// ---------------------------------------------------------------------------
__global__ __launch_bounds__(256) void cvt_f32_bf16(const float* __restrict__ src,
                                                    bf16* __restrict__ dst, long n) {
  const long stride4 = (long)gridDim.x * blockDim.x * 4;
  for (long j = ((long)blockIdx.x * blockDim.x + threadIdx.x) * 4; j < n; j += stride4) {
    const float4 v = *(const float4*)(src + j);
    bf16x4 o;
    o[0] = (bf16)v.x; o[1] = (bf16)v.y; o[2] = (bf16)v.z; o[3] = (bf16)v.w;
    *(bf16x4*)(dst + j) = o;
  }
}

// ---------------------------------------------------------------------------
// gemm256: C[i,j] = sum_k A[i,k]*B[j,k], K=1024. A:[M,1024] B:[N,1024] bf16.
// Grid: dim3(N/256, M/256), 512 threads. Requires M%256==0, N%256==0,
// (gx*gy)%8==0, reluRows%256==0.
// ---------------------------------------------------------------------------
template <int LDC, typename CO>
__global__ __launch_bounds__(512, 2) void gemm256(const bf16* __restrict__ A,
                                                  const bf16* __restrict__ Bm,
                                                  CO* __restrict__ Co,
                                                  const float* __restrict__ bias,
                                                  const int reluRows) {
  __shared__ bf16 As[2][256 * 64];
  __shared__ bf16 Bs[2][256 * 64];
  const int tid  = threadIdx.x;
  const int lane = tid & 63;
  const int w    = tid >> 6;      // wave 0..7
  const int wm   = w >> 2;        // 2 M-halves
  const int wn   = w & 3;         // 4 N-quarters

  // T1: bijective XCD swizzle; smaller grid dim innermost (operand-panel reuse)
  const int gx = gridDim.x, gy = gridDim.y;
  const int nwg = gx * gy;
  const int id  = blockIdx.x + gx * blockIdx.y;
  const int sid = (id & 7) * (nwg >> 3) + (id >> 3);
  int bx, by;
  if (gx < gy) { bx = sid % gx; by = sid / gx; }
  else         { by = sid % gy; bx = sid / gy; }
  const int i0 = by * 256;
  const int j0 = bx * 256;

  // Staging geometry: instruction q covers tile rows 64q..64q+63; wave w rows
  // 64q+8w..+7; lane l -> row lr = l>>3, 16B-chunk lc = (l&7)^lr (pre-swizzled
  // global source so that linear LDS holds the XOR-swizzled layout).
  const int lr = lane >> 3;
  const int lc = (lane & 7) ^ lr;
  const bf16* Agl = A  + (long)(i0 + 8 * w + lr) * 1024 + lc * 8;
  const bf16* Bgl = Bm + (long)(j0 + 8 * w + lr) * 1024 + lc * 8;
  const int wofs = w * 512;  // (8w rows) * 64 elems

  // ds_read geometry: logical (row, chunk c) lives at byte row*128 + (c^(row&7))*16.
  const int r15 = lane & 15, g = lane >> 4;
  const int ck[2] = { ((0 + g) ^ (r15 & 7)) * 8, ((4 + g) ^ (r15 & 7)) * 8 };
  const int arow = (wm * 128 + r15) * 64;
  const int brow = (wn * 64 + r15) * 64;

  f32x4 acc[8][4] = {};

  // prologue: stage tile 0 -> buf 0 (8 loads)
#pragma unroll
  for (int q = 0; q < 4; ++q) {
    gload_lds16(Agl + q * 65536, &As[0][q * 4096 + wofs]);
    gload_lds16(Bgl + q * 65536, &Bs[0][q * 4096 + wofs]);
  }

  for (int kt = 0; kt < 16; ++kt) {
    const int cur = kt & 1;
    if (kt < 15) {
      const long ko = (long)(kt + 1) * 64;
#pragma unroll
      for (int q = 0; q < 4; ++q) {
        gload_lds16(Agl + ko + q * 65536, &As[cur ^ 1][q * 4096 + wofs]);
        gload_lds16(Bgl + ko + q * 65536, &Bs[cur ^ 1][q * 4096 + wofs]);
      }
      // counted: wait for tile kt's 8 loads; tile kt+1's 8 stay in flight
      asm volatile("s_waitcnt vmcnt(8)" ::: "memory");
    } else {
      asm volatile("s_waitcnt vmcnt(0)" ::: "memory");
    }
    __builtin_amdgcn_s_barrier();       // all waves' tile-kt loads visible
    __builtin_amdgcn_sched_barrier(0);  // no ds_read hoists above the barrier

    const bf16* Ab = &As[cur][arow];
    const bf16* Bb = &Bs[cur][brow];
#pragma unroll
    for (int ks = 0; ks < 2; ++ks) {
      bf16x8 af[8], bfr[4];
#pragma unroll
      for (int fm = 0; fm < 8; ++fm)
        af[fm] = *(const bf16x8*)(Ab + fm * 1024 + ck[ks]);
#pragma unroll
      for (int fn = 0; fn < 4; ++fn)
        bfr[fn] = *(const bf16x8*)(Bb + fn * 1024 + ck[ks]);
      __builtin_amdgcn_s_setprio(1);
#pragma unroll
      for (int fm = 0; fm < 8; ++fm)
#pragma unroll
        for (int fn = 0; fn < 4; ++fn)
          acc[fm][fn] = MFMA16(af[fm], bfr[fn], acc[fm][fn]);
      __builtin_amdgcn_s_setprio(0);
    }
    // drain this wave's LDS reads, then join: after this barrier every wave's
    // reads of buf[cur] are complete -> next iter may re-stage into it.
    asm volatile("s_waitcnt lgkmcnt(0)" ::: "memory");
    __builtin_amdgcn_sched_barrier(0);
    __builtin_amdgcn_s_barrier();
  }

  // Epilogue. D layout per 16x16 tile: row = g*4 + jj, col = r15.
  const bool doRelu = (i0 < reluRows);
#pragma unroll
  for (int fm = 0; fm < 8; ++fm) {
    const int r0 = i0 + wm * 128 + fm * 16 + g * 4;
#pragma unroll
    for (int fn = 0; fn < 4; ++fn) {
      const int cc = j0 + wn * 64 + fn * 16 + r15;
      const float bv = bias ? bias[cc] : 0.0f;
#pragma unroll
      for (int jj = 0; jj < 4; ++jj) {
        float v = acc[fm][fn][jj] + bv;
        if (doRelu) v = fmaxf(v, 0.0f);
        Co[(long)(r0 + jj) * LDC + cc] = (CO)v;
      }
    }
  }
}

// ---------------------------------------------------------------------------
// K2: per (b,h) n-chunk s (512 cols): partial ctx[d,e] += V[d,n]*K[e,n],
//     partial ksum[e] += K[e,n].  Direct global->MFMA (no LDS), deterministic.
// ---------------------------------------------------------------------------
__global__ __launch_bounds__(256) void ctx_kernel(const bf16* __restrict__ QKV,
                                                  float* __restrict__ ctx_part,
                                                  float* __restrict__ ksum_part) {
  const int bh = blockIdx.x;  // 0..63
  const int s  = blockIdx.y;  // 0..7
  const int b  = bh >> 4, h = bh & 15;
  const int tid = threadIdx.x, lane = tid & 63, w = tid >> 6;
  const long ldq = 16384;
  const bf16* Kp = QKV + (long)(1024 + h * 64) * ldq + b * 4096 + s * 512;
  const bf16* Vp = QKV + (long)(2048 + h * 64) * ldq + b * 4096 + s * 512;

  const int r15  = lane & 15;
  const int koff = (lane >> 4) * 8;

  f32x4 acc[4] = {};  // wave w owns d rows [w*16, w*16+16), 4 e-tiles
#pragma unroll 4
  for (int n = 0; n < 512; n += 32) {
    const bf16x8 a = *(const bf16x8*)(Vp + (long)(w * 16 + r15) * ldq + n + koff);
#pragma unroll
    for (int u = 0; u < 4; ++u) {
      const bf16x8 kb = *(const bf16x8*)(Kp + (long)(u * 16 + r15) * ldq + n + koff);
      acc[u] = MFMA16(a, kb, acc[u]);
    }
  }
  float* cp = ctx_part + (long)(bh * 8 + s) * 4096;
#pragma unroll
  for (int u = 0; u < 4; ++u)
#pragma unroll
    for (int jj = 0; jj < 4; ++jj) {
      const int d = w * 16 + (lane >> 4) * 4 + jj;
      const int e = u * 16 + r15;
      cp[d * 64 + e] = acc[u][jj];
    }

  // ksum partial: 4 threads per e-row, 128 cols each
  const int e = tid >> 2, q4 = tid & 3;
  const bf16* kr = Kp + (long)e * ldq + q4 * 128;
  float sum = 0.0f;
#pragma unroll
  for (int i = 0; i < 128; i += 8) {
    const bf16x8 v = *(const bf16x8*)(kr + i);
#pragma unroll
    for (int jj = 0; jj < 8; ++jj) sum += (float)v[jj];
  }
  sum += __shfl_xor(sum, 1);
  sum += __shfl_xor(sum, 2);
  if (q4 == 0) ksum_part[(bh * 8 + s) * 64 + e] = sum;
}

// ---------------------------------------------------------------------------
// K3: per (b,h), 256-col n-chunk: O[(b,n), h*64+d] = z[n]*sum_e ctx[d,e]Q[e,n]
// ---------------------------------------------------------------------------
__global__ __launch_bounds__(256) void out_kernel(const bf16* __restrict__ QKV,
                                                  const float* __restrict__ ctx_part,
                                                  const float* __restrict__ ksum_part,
                                                  bf16* __restrict__ O) {
  __shared__ bf16 ctx_lds[64 * 88];   // [d][e], stride 88 (176B, 16B-mult, ~2-way)
  __shared__ bf16 qlds[256 * 80];     // [n_local][e], stride 80 (160B, 16B-mult)
  __shared__ float ksum_lds[64];
  __shared__ float zlds[256];

  const int nc = blockIdx.x;  // 0..15
  const int bh = blockIdx.y;  // 0..63
  const int b = bh >> 4, h = bh & 15;
  const int tid = threadIdx.x, lane = tid & 63, w = tid >> 6;
  const int n0 = nc * 256;
  const long ldq = 16384;

  // 1) sum 8 ctx partials -> bf16 LDS
  const float* cp = ctx_part + (long)bh * 8 * 4096;
#pragma unroll
  for (int r = 0; r < 16; ++r) {
    const int idx = tid + r * 256;  // = d*64 + e
    float v = 0.0f;
#pragma unroll
    for (int s2 = 0; s2 < 8; ++s2) v += cp[s2 * 4096 + idx];
    ctx_lds[(idx >> 6) * 88 + (idx & 63)] = (bf16)v;
  }
  if (tid < 64) {
    float v = 0.0f;
#pragma unroll
    for (int s2 = 0; s2 < 8; ++s2) v += ksum_part[(bh * 8 + s2) * 64 + tid];
    ksum_lds[tid] = v;
  }
  // 2) stage Q tile transposed: qlds[n][e]
  {
    const bf16* Qp = QKV + (long)(h * 64) * ldq + b * 4096 + n0;
    const int e = tid >> 2, seg = tid & 3;
    const bf16* qr = Qp + (long)e * ldq + seg * 64;
#pragma unroll
    for (int i = 0; i < 64; i += 8) {
      const bf16x8 v = *(const bf16x8*)(qr + i);
#pragma unroll
      for (int jj = 0; jj < 8; ++jj) qlds[(seg * 64 + i + jj) * 80 + e] = v[jj];
    }
  }
  __syncthreads();

  // 3) z[n] = 1/(ksum . Q[:,n] + eps)
  {
    float a = 0.0f;
    const bf16* qrow = qlds + tid * 80;
#pragma unroll
    for (int d = 0; d < 64; ++d) a += (float)qrow[d] * ksum_lds[d];
    zlds[tid] = 1.0f / (a + 1.1920929e-07f);
  }
  // A-frags (ctx) once per wave: 4 d-tiles x 2 k(e)-steps
  const int r15 = lane & 15;
  const int koff = (lane >> 4) * 8;
  bf16x8 afr[4][2];
#pragma unroll
  for (int t = 0; t < 4; ++t)
#pragma unroll
    for (int s2 = 0; s2 < 2; ++s2)
      afr[t][s2] = *(const bf16x8*)(ctx_lds + (t * 16 + r15) * 88 + s2 * 32 + koff);
  __syncthreads();

  // 4) each wave: 4 n-tiles of 16
#pragma unroll
  for (int nt = 0; nt < 4; ++nt) {
    const int ntile = w * 4 + nt;
    bf16x8 bfr[2];
#pragma unroll
    for (int s2 = 0; s2 < 2; ++s2)
      bfr[s2] = *(const bf16x8*)(qlds + (ntile * 16 + r15) * 80 + s2 * 32 + koff);
    f32x4 accn[4] = {};
#pragma unroll
    for (int t = 0; t < 4; ++t) {
      accn[t] = MFMA16(afr[t][0], bfr[0], accn[t]);
      accn[t] = MFMA16(afr[t][1], bfr[1], accn[t]);
    }
    const int ncol = n0 + ntile * 16 + r15;
    const float zv = zlds[ntile * 16 + r15];
    bf16* orow = O + (long)(b * 4096 + ncol) * 1024 + h * 64;
#pragma unroll
    for (int t = 0; t < 4; ++t) {
      const int d0 = t * 16 + (lane >> 4) * 4;
      bf16x4 pk;
#pragma unroll
      for (int jj = 0; jj < 4; ++jj) pk[jj] = (bf16)(accn[t][jj] * zv);
      *(bf16x4*)(orow + d0) = pk;  // 8B store, 4 consecutive d
    }
  }
}

// ---------------------------------------------------------------------------
extern "C" void kernel_launch(void* const* d_in, const int* in_sizes, int n_in,
                              void* d_out, int out_size, void* d_ws, size_t ws_size,
                              hipStream_t stream) {
  const float* x      = (const float*)d_in[0];  // [4,4096,1024] fp32
  const float* w_qkv  = (const float*)d_in[1];  // [3072,1024]   fp32
  const float* w_proj = (const float*)d_in[2];  // [1024,1024]   fp32
  const float* b_proj = (const float*)d_in[3];  // [1024]        fp32
  float* out = (float*)d_out;                   // [4,4096,1024] fp32

  char* ws = (char*)d_ws;
  // Layout (xb region reused for O after K1):
  bf16*  QKV       = (bf16*)ws;                               // 96 MiB
  float* ctx_part  = (float*)(ws + 100663296);                // 8 MiB
  float* ksum_part = (float*)(ws + 100663296 + 8388608);      // 128 KiB
  bf16*  xb        = (bf16*)(ws + 109182976);                 // 32 MiB (K1 input)
  bf16*  O         = xb;                                      // reuse after K1
  bf16*  wqkvb     = (bf16*)(ws + 109182976 + 33554432);      // 6 MiB
  bf16*  wprojb    = (bf16*)(ws + 109182976 + 33554432 + 6291456);  // 2 MiB

  // K0: fp32 -> bf16 conversions
  cvt_f32_bf16<<<2048, 256, 0, stream>>>(x,      xb,     16777216);
  cvt_f32_bf16<<<512,  256, 0, stream>>>(w_qkv,  wqkvb,  3145728);
  cvt_f32_bf16<<<256,  256, 0, stream>>>(w_proj, wprojb, 1048576);
  // K1: QKV^T[c,m] = sum_k w_qkv[c,k]*x[m,k]; relu rows c<2048. M=3072, N=16384.
  gemm256<16384, bf16><<<dim3(64, 12), 512, 0, stream>>>(wqkvb, xb, QKV, nullptr, 2048);
  // K2: partial ctx + ksum
  ctx_kernel<<<dim3(64, 8), 256, 0, stream>>>(QKV, ctx_part, ksum_part);
  // K3: O[m, c]  (overwrites xb region — xb dead after K1)
  out_kernel<<<dim3(16, 64), 256, 0, stream>>>(QKV, ctx_part, ksum_part, O);
  // K4: out[m,co] = sum_c O[m,c]*w_proj[co,c] + b_proj. M=16384, N=1024, fp32 out.
  gemm256<1024, float><<<dim3(4, 64), 512, 0, stream>>>(O, wprojb, out, b_proj, 0);
}